// Round 1
// 2003.562 us; speedup vs baseline: 1.3539x; 1.3539x over previous
//
#include <hip/hip_runtime.h>

// GraphWaveNet block: gated inception conv -> 2x mixprop (fwd/rev) + residual, skip = h@Ws+bs
// B=8 T=256 N=512 C=64. All heavy GEMMs in bf16 MFMA 16x16x32, fp32 accum.
//
// v2: diffusion GEMMs (A*H, A*P1) hoisted out of the per-(b,t) monolith into batched
// MFMA GEMMs over the full [512 x 131072] H matrix; W2 folded into the P2 epilogue so
// all intermediates fit in out/skip scratch:
//   skip-slot[bt] (128KB) = [ H[bt] 64KB | P1f[bt] 64KB ]
//   out-slot[bt]  (128KB) = [ P1r[bt] 64KB | V[bt] 64KB ]   V = (Af*P1f)*W2f + (Ar*P1r)*W2r
// k_out then does only 3 stage+proj phases + elementwise epilogue.

typedef short     s16x8 __attribute__((ext_vector_type(8)));
typedef unsigned short u16x4 __attribute__((ext_vector_type(4)));
typedef float     f32x4 __attribute__((ext_vector_type(4)));
typedef float     f32x4v __attribute__((ext_vector_type(4)));

__device__ __forceinline__ unsigned short f2bf(float f){
  union { float f; unsigned u; } v; v.f = f;
  unsigned r = v.u + 0x7FFFu + ((v.u >> 16) & 1u);   // RNE
  return (unsigned short)(r >> 16);
}

__device__ __forceinline__ float bf2f(unsigned short u){
  union { unsigned u; float f; } v; v.u = ((unsigned)u) << 16;
  return v.f;
}

__device__ __forceinline__ f32x4 mfma16(s16x8 a, s16x8 b, f32x4 c){
  return __builtin_amdgcn_mfma_f32_16x16x32_bf16(a, b, c, 0, 0, 0);
}

// ---------------- preprocess: row-normalized adjacency (fwd + rev), bf16 ----------------
__global__ void k_adj(const float* __restrict__ adj,
                      unsigned short* __restrict__ Af,
                      unsigned short* __restrict__ Ar){
  __shared__ float red[256];
  int n = blockIdx.x, tid = threadIdx.x;
  float rv0 = adj[n*512 + tid], rv1 = adj[n*512 + tid + 256];
  red[tid] = rv0 + rv1; __syncthreads();
  for (int o = 128; o > 0; o >>= 1){ if (tid < o) red[tid] += red[tid+o]; __syncthreads(); }
  float rs = red[0] + 1.0f;           // + self loop
  __syncthreads();
  float cv0 = adj[tid*512 + n], cv1 = adj[(tid+256)*512 + n];
  red[tid] = cv0 + cv1; __syncthreads();
  for (int o = 128; o > 0; o >>= 1){ if (tid < o) red[tid] += red[tid+o]; __syncthreads(); }
  float cs = red[0] + 1.0f;
  float ir = 1.0f / fmaxf(rs, 1e-9f), ic = 1.0f / fmaxf(cs, 1e-9f);
  Af[n*512 + tid]       = f2bf((rv0 + (tid==n ? 1.f:0.f)) * ir);
  Af[n*512 + tid + 256] = f2bf((rv1 + (tid+256==n ? 1.f:0.f)) * ir);
  Ar[n*512 + tid]       = f2bf((cv0 + (tid==n ? 1.f:0.f)) * ic);
  Ar[n*512 + tid + 256] = f2bf((cv1 + (tid+256==n ? 1.f:0.f)) * ic);
}

// ------------- preprocess: concat conv weights into B^T layout [cout][d*64+cin] bf16 -------------
__global__ void k_wcat(const float* __restrict__ wf0, const float* __restrict__ wf1,
                       const float* __restrict__ wf2, const float* __restrict__ wf3,
                       const float* __restrict__ wg0, const float* __restrict__ wg1,
                       const float* __restrict__ wg2, const float* __restrict__ wg3,
                       unsigned short* __restrict__ WF, unsigned short* __restrict__ WG){
  int id = blockIdx.x * 256 + threadIdx.x;
  if (id >= 64*448) return;
  int cout = id / 448, k = id % 448;
  int d = k >> 6, cin = k & 63;
  int br = cout >> 4, j = cout & 15;
  int kb = (br==0)?2:(br==1)?3:(br==2)?6:7;
  float vf = 0.f, vg = 0.f;
  if (d < kb){
    int tau = kb - 1 - d;
    const float* wf = (br==0)?wf0:(br==1)?wf1:(br==2)?wf2:wf3;
    const float* wg = (br==0)?wg0:(br==1)?wg1:(br==2)?wg2:wg3;
    vf = wf[(tau*64 + cin)*16 + j];
    vg = wg[(tau*64 + cin)*16 + j];
  }
  WF[id] = f2bf(vf);
  WG[id] = f2bf(vg);
}

// ------------- preprocess: folded projection weights, B^T layout [cout][cin] bf16 -------------
__global__ void k_wtil(const float* __restrict__ Wgf, const float* __restrict__ Wgr,
                       const float* __restrict__ Ws,
                       unsigned short* __restrict__ W0, unsigned short* __restrict__ W1f,
                       unsigned short* __restrict__ W2f, unsigned short* __restrict__ W1r,
                       unsigned short* __restrict__ W2r, unsigned short* __restrict__ WsT){
  int id = blockIdx.x*256 + threadIdx.x;
  if (id >= 4096) return;
  int cout = id >> 6, cin = id & 63;
  const float a = 0.05f, b = 0.95f;
  float f0 = Wgf[cin*64+cout], f1 = Wgf[(64+cin)*64+cout], f2 = Wgf[(128+cin)*64+cout];
  float r0 = Wgr[cin*64+cout], r1 = Wgr[(64+cin)*64+cout], r2 = Wgr[(128+cin)*64+cout];
  int o = cout*64 + cin;
  W0[o]  = f2bf(f0 + a*(f1+f2) + r0 + a*(r1+r2));
  W1f[o] = f2bf(b*f1 + a*b*f2);
  W2f[o] = f2bf(b*b*f2);
  W1r[o] = f2bf(b*r1 + a*b*r2);
  W2r[o] = f2bf(b*b*r2);
  WsT[o] = f2bf(Ws[cin*64+cout]);
}

// ---------------- gated inception conv: h = tanh(f)*sigmoid(g), bf16, written as [b,t,c,n] ----------------
__global__ __launch_bounds__(256, 4)
void k_conv(const float* __restrict__ x,
            const unsigned short* __restrict__ WF, const unsigned short* __restrict__ WG,
            const float* __restrict__ bf0, const float* __restrict__ bf1,
            const float* __restrict__ bf2, const float* __restrict__ bf3,
            const float* __restrict__ bg0, const float* __restrict__ bg1,
            const float* __restrict__ bg2, const float* __restrict__ bg3,
            unsigned short* __restrict__ hT){
  __shared__ __align__(16) unsigned short Xw[7*64*64];
  int tid = threadIdx.x;
  int t0 = blockIdx.x * 32, n0 = blockIdx.y * 64, b = blockIdx.z;
  int w = tid >> 6, lane = tid & 63, q = lane >> 4, lr = lane & 15;
  int kw = (w==0)?2:(w==1)?3:(w==2)?6:7;
  const float* bfp = (w==0)?bf0:(w==1)?bf1:(w==2)?bf2:bf3;
  const float* bgp = (w==0)?bg0:(w==1)?bg1:(w==2)?bg2:bg3;
  float bfv = bfp[lr], bgv = bgp[lr];
  int cout = w*16 + lr;

  auto stage = [&](int tau){
    int slot = (tau + 7) % 7;
    #pragma unroll
    for (int i = 0; i < 4; ++i){
      int fidx = i*256 + tid;
      int n = fidx >> 4, c = (fidx & 15) * 4;
      f32x4v v = {0.f, 0.f, 0.f, 0.f};
      if (tau >= 0){
        v = *(const f32x4v*)&x[(((b*256 + tau)*512) + n0 + n)*64 + c];
      }
      u16x4 p; p[0]=f2bf(v[0]); p[1]=f2bf(v[1]); p[2]=f2bf(v[2]); p[3]=f2bf(v[3]);
      int addr = slot*4096 + n*64 + ((((c>>3) ^ (n&7)) & 7) << 3) + (c & 7);
      *(u16x4*)&Xw[addr] = p;
    }
  };
  for (int tau = t0-6; tau <= t0; ++tau) stage(tau);
  __syncthreads();

  for (int tl = 0; tl < 32; ++tl){
    int t = t0 + tl;
    f32x4 accf[4], accg[4];
    #pragma unroll
    for (int mi = 0; mi < 4; ++mi){ accf[mi] = (f32x4){0,0,0,0}; accg[mi] = (f32x4){0,0,0,0}; }
    for (int d = 0; d < kw; ++d){
      int slot = (t - d + 7) % 7;
      #pragma unroll
      for (int kk = 0; kk < 2; ++kk){
        int kbase = d*64 + kk*32 + q*8;
        s16x8 bfr = *(const s16x8*)&WF[cout*448 + kbase];
        s16x8 bgr_ = *(const s16x8*)&WG[cout*448 + kbase];
        #pragma unroll
        for (int mi = 0; mi < 4; ++mi){
          int n = mi*16 + lr;
          int cb = kk*4 + q;
          s16x8 a = *(const s16x8*)&Xw[slot*4096 + n*64 + (((cb ^ (n&7)) & 7) << 3)];
          accf[mi] = mfma16(a, bfr, accf[mi]);
          accg[mi] = mfma16(a, bgr_, accg[mi]);
        }
      }
    }
    unsigned short* hs = hT + (size_t)(b*256 + t) * 65536;
    #pragma unroll
    for (int mi = 0; mi < 4; ++mi){
      u16x4 pv;
      #pragma unroll
      for (int r = 0; r < 4; ++r){
        float f = accf[mi][r] + bfv;
        float g = accg[mi][r] + bgv;
        float th = 2.f / (1.f + __expf(-2.f*f)) - 1.f;
        float sg = 1.f / (1.f + __expf(-g));
        pv[r] = f2bf(th * sg);
      }
      *(u16x4*)&hs[cout*512 + (n0 + mi*16 + q*4)] = pv;
    }
    __syncthreads();
    if (tl < 31){ stage(t+1); __syncthreads(); }
  }
}

// ---------------- batched dual-A GEMM: P1f = Af*H, P1r = Ar*H ----------------
// grid (512 btc-tiles of 4 bt, 4 n-tiles of 128), 512 threads = 8 waves (2n x 4bt).
// B-stream: hT rows [bt][c][m] are exactly B^T row-slices; staged to LDS with XOR swizzle.
__global__ __launch_bounds__(512, 2)
void k_pp(const unsigned short* __restrict__ Af, const unsigned short* __restrict__ Ar,
          unsigned short* __restrict__ skipU, unsigned short* __restrict__ outU){
  __shared__ __align__(16) unsigned short B[2][16384];   // 2 x 32KB: [256 col][64 m]
  int tid = threadIdx.x;
  int bx = blockIdx.x;            // btc tile (4 bt)
  int nt = blockIdx.y;            // n tile (128 rows)
  int w = tid >> 6, lane = tid & 63, q = lane >> 4, lr = lane & 15;
  int wn = w >> 2, wc = w & 3;
  int bt = bx*4 + wc;
  int nb = nt*128 + wn*64;

  f32x4 accF[4][4], accR[4][4];
  #pragma unroll
  for (int i=0;i<4;i++){
    #pragma unroll
    for (int j=0;j<4;j++){ accF[i][j] = (f32x4){0,0,0,0}; accR[i][j] = (f32x4){0,0,0,0}; }
  }

  auto stage = [&](int kt, int buf){
    int k0 = kt*64;
    #pragma unroll
    for (int p = 0; p < 4; ++p){
      int idx = p*512 + tid;
      int row = idx >> 3;               // col index (bt-local*64 + c)
      int inner = (idx & 7) << 4;       // byte within 128B row
      int btl = row >> 6, c = row & 63;
      s16x8 v = *(const s16x8*)&skipU[(size_t)(bx*4 + btl)*65536 + c*512 + k0 + (inner>>1)];
      int dst = row*128 + (inner ^ ((row & 7) << 4));
      *(s16x8*)((char*)&B[buf][0] + dst) = v;
    }
  };

  stage(0, 0); __syncthreads();
  for (int kt = 0; kt < 8; ++kt){
    int buf = kt & 1;
    if (kt < 7) stage(kt+1, buf^1);
    int k0 = kt*64;
    #pragma unroll
    for (int kk = 0; kk < 2; ++kk){
      s16x8 bfrag[4];
      #pragma unroll
      for (int ni = 0; ni < 4; ++ni){
        int col = wc*64 + ni*16 + lr;
        int byt = col*128 + (((kk<<6) + (q<<4)) ^ ((col & 7) << 4));
        bfrag[ni] = *(const s16x8*)((const char*)&B[buf][0] + byt);
      }
      #pragma unroll
      for (int mi = 0; mi < 4; ++mi){
        size_t ao = (size_t)(nb + mi*16 + lr)*512 + k0 + kk*32 + q*8;
        s16x8 av  = *(const s16x8*)&Af[ao];
        s16x8 arv = *(const s16x8*)&Ar[ao];
        #pragma unroll
        for (int ni = 0; ni < 4; ++ni){
          accF[mi][ni] = mfma16(av,  bfrag[ni], accF[mi][ni]);
          accR[mi][ni] = mfma16(arv, bfrag[ni], accR[mi][ni]);
        }
      }
    }
    __syncthreads();
  }

  // epilogue: per-wave 64x64 transpose via LDS patch (stride 72), store [c][n] rows
  unsigned short* pat = &B[0][0] + w*2304;
  auto xstore = [&](f32x4 (*acc)[4], unsigned short* dst){
    #pragma unroll
    for (int hh = 0; hh < 2; ++hh){
      #pragma unroll
      for (int ni2 = 0; ni2 < 2; ++ni2){
        int ni = hh*2 + ni2;
        int cl = ni2*16 + lr;
        #pragma unroll
        for (int mi = 0; mi < 4; ++mi){
          u16x4 v;
          v[0]=f2bf(acc[mi][ni][0]); v[1]=f2bf(acc[mi][ni][1]);
          v[2]=f2bf(acc[mi][ni][2]); v[3]=f2bf(acc[mi][ni][3]);
          *(u16x4*)&pat[cl*72 + mi*16 + q*4] = v;
        }
      }
      #pragma unroll
      for (int p = 0; p < 4; ++p){
        int cl = p*8 + (lane>>3);
        int nl = (lane&7)*8;
        s16x8 v = *(const s16x8*)&pat[cl*72 + nl];
        *(s16x8*)&dst[(size_t)(hh*32 + cl)*512 + nb + nl] = v;
      }
    }
  };
  xstore(accF, skipU + (size_t)bt*65536 + 32768);   // P1f -> skip-slot hi
  xstore(accR, outU  + (size_t)bt*65536);           // P1r -> out-slot lo
}

// ---------------- batched GEMM + W2 fold: V (+)= (A * P1x) * W2x ----------------
__global__ __launch_bounds__(512, 2)
void k_p2(const unsigned short* __restrict__ A, const unsigned short* __restrict__ srcU,
          const unsigned short* __restrict__ W2T, unsigned short* __restrict__ outU, int addv){
  __shared__ __align__(16) unsigned short B[2][16384];
  int tid = threadIdx.x;
  int bx = blockIdx.x;
  int nt = blockIdx.y;
  int w = tid >> 6, lane = tid & 63, q = lane >> 4, lr = lane & 15;
  int wn = w >> 2, wc = w & 3;
  int bt = bx*4 + wc;
  int nb = nt*128 + wn*64;

  f32x4 acc[4][4];
  #pragma unroll
  for (int i=0;i<4;i++){
    #pragma unroll
    for (int j=0;j<4;j++) acc[i][j] = (f32x4){0,0,0,0};
  }

  auto stage = [&](int kt, int buf){
    int k0 = kt*64;
    #pragma unroll
    for (int p = 0; p < 4; ++p){
      int idx = p*512 + tid;
      int row = idx >> 3;
      int inner = (idx & 7) << 4;
      int btl = row >> 6, c = row & 63;
      s16x8 v = *(const s16x8*)&srcU[(size_t)(bx*4 + btl)*65536 + c*512 + k0 + (inner>>1)];
      int dst = row*128 + (inner ^ ((row & 7) << 4));
      *(s16x8*)((char*)&B[buf][0] + dst) = v;
    }
  };

  stage(0, 0); __syncthreads();
  for (int kt = 0; kt < 8; ++kt){
    int buf = kt & 1;
    if (kt < 7) stage(kt+1, buf^1);
    int k0 = kt*64;
    #pragma unroll
    for (int kk = 0; kk < 2; ++kk){
      s16x8 bfrag[4];
      #pragma unroll
      for (int ni = 0; ni < 4; ++ni){
        int col = wc*64 + ni*16 + lr;
        int byt = col*128 + (((kk<<6) + (q<<4)) ^ ((col & 7) << 4));
        bfrag[ni] = *(const s16x8*)((const char*)&B[buf][0] + byt);
      }
      #pragma unroll
      for (int mi = 0; mi < 4; ++mi){
        s16x8 av = *(const s16x8*)&A[(size_t)(nb + mi*16 + lr)*512 + k0 + kk*32 + q*8];
        #pragma unroll
        for (int ni = 0; ni < 4; ++ni)
          acc[mi][ni] = mfma16(av, bfrag[ni], acc[mi][ni]);
      }
    }
    __syncthreads();
  }

  // epilogue: vacc = (acc as P2[n][c]) * W2  via per-wave LDS transpose patch
  unsigned short* pat = &B[0][0] + w*2304;
  f32x4 vacc[4][4];
  #pragma unroll
  for (int i=0;i<4;i++){
    #pragma unroll
    for (int j=0;j<4;j++) vacc[i][j] = (f32x4){0,0,0,0};
  }
  #pragma unroll
  for (int hh = 0; hh < 2; ++hh){
    #pragma unroll
    for (int ni2 = 0; ni2 < 2; ++ni2){
      int ni = hh*2 + ni2;
      int cl = ni2*16 + lr;
      #pragma unroll
      for (int mi = 0; mi < 4; ++mi){
        u16x4 v;
        v[0]=f2bf(acc[mi][ni][0]); v[1]=f2bf(acc[mi][ni][1]);
        v[2]=f2bf(acc[mi][ni][2]); v[3]=f2bf(acc[mi][ni][3]);
        *(u16x4*)&pat[cl*72 + mi*16 + q*4] = v;
      }
    }
    #pragma unroll
    for (int mi = 0; mi < 4; ++mi){
      s16x8 avf;
      #pragma unroll
      for (int j = 0; j < 8; ++j) avf[j] = (short)pat[(q*8 + j)*72 + mi*16 + lr];
      #pragma unroll
      for (int ni = 0; ni < 4; ++ni){
        s16x8 bw = *(const s16x8*)&W2T[(ni*16 + lr)*64 + hh*32 + q*8];
        vacc[mi][ni] = mfma16(avf, bw, vacc[mi][ni]);
      }
    }
  }
  // store / accumulate V[bt][n][c'] in out-slot hi
  size_t vbase = (size_t)bt*65536 + 32768;
  #pragma unroll
  for (int mi = 0; mi < 4; ++mi){
    #pragma unroll
    for (int ni = 0; ni < 4; ++ni){
      #pragma unroll
      for (int r = 0; r < 4; ++r){
        int n = nb + mi*16 + q*4 + r;
        size_t adr = vbase + (size_t)n*64 + ni*16 + lr;
        float val = vacc[mi][ni][r];
        if (addv) val += bf2f(outU[adr]);
        outU[adr] = f2bf(val);
      }
    }
  }
}

// ---------------- projections + skip + residual epilogue (per (b,t)) ----------------
__global__ __launch_bounds__(512, 2)
void k_out(const float* __restrict__ x,
           unsigned short* __restrict__ skipU, unsigned short* __restrict__ outU,
           const unsigned short* __restrict__ W0, const unsigned short* __restrict__ W1f,
           const unsigned short* __restrict__ W1r, const unsigned short* __restrict__ WsT,
           const float* __restrict__ bgf, const float* __restrict__ bgr,
           const float* __restrict__ bs,
           float* __restrict__ outp, float* __restrict__ skipp){
  __shared__ __align__(16) unsigned short Hb[64*512];
  int tid = threadIdx.x;
  int t = blockIdx.x, b = blockIdx.y;
  int bt = b*256 + t;
  int w = tid >> 6, lane = tid & 63, q = lane >> 4, lr = lane & 15;
  unsigned short* slotS = skipU + (size_t)bt*65536;
  unsigned short* slotO = outU  + (size_t)bt*65536;

  f32x4 oacc[4][4];
  #pragma unroll
  for (int i=0;i<4;i++){
    #pragma unroll
    for (int j=0;j<4;j++) oacc[i][j] = (f32x4){0,0,0,0};
  }

  auto haddr = [&](int c, int n){
    int sw = ((((n>>3)&7) ^ (c&7)) + (c>>3)) & 7;
    return c*512 + (n & 448) + sw*8 + (n & 7);
  };
  auto stageX = [&](const unsigned short* src){
    #pragma unroll
    for (int i = 0; i < 8; ++i){
      int fidx = i*512 + tid;
      int c = fidx >> 6, jb = fidx & 63;
      s16x8 v = *(const s16x8*)&src[c*512 + jb*8];
      int sw = (((jb & 7) ^ (c & 7)) + (c >> 3)) & 7;
      *(s16x8*)&Hb[c*512 + (jb & 56)*8 + sw*8] = v;
    }
  };
  auto proj = [&](const unsigned short* __restrict__ Wt, f32x4 (*acc)[4]){
    #pragma unroll
    for (int k2 = 0; k2 < 2; ++k2){
      s16x8 af[4];
      #pragma unroll
      for (int mi = 0; mi < 4; ++mi){
        int n = w*64 + mi*16 + lr;
        s16x8 tv;
        #pragma unroll
        for (int j = 0; j < 8; ++j){
          int c = k2*32 + q*8 + j;
          tv[j] = (short)Hb[haddr(c, n)];
        }
        af[mi] = tv;
      }
      #pragma unroll
      for (int ni = 0; ni < 4; ++ni){
        s16x8 bw = *(const s16x8*)&Wt[(ni*16 + lr)*64 + k2*32 + q*8];
        #pragma unroll
        for (int mi = 0; mi < 4; ++mi)
          acc[mi][ni] = mfma16(af[mi], bw, acc[mi][ni]);
      }
    }
  };

  // P1f -> W1f
  stageX(slotS + 32768); __syncthreads();
  proj(W1f, oacc); __syncthreads();
  // H -> W0, Ws(skip)
  stageX(slotS); __syncthreads();
  proj(W0, oacc);
  {
    f32x4 sacc[4][4];
    #pragma unroll
    for (int i=0;i<4;i++){
      #pragma unroll
      for (int j=0;j<4;j++) sacc[i][j] = (f32x4){0,0,0,0};
    }
    proj(WsT, sacc);
    float* sp = skipp + (size_t)bt*32768;   // overwrites H|P1f: all global reads done
    #pragma unroll
    for (int ni = 0; ni < 4; ++ni){
      float bsv = bs[ni*16 + lr];
      #pragma unroll
      for (int mi = 0; mi < 4; ++mi){
        #pragma unroll
        for (int r = 0; r < 4; ++r)
          sp[(w*64 + mi*16 + q*4 + r)*64 + ni*16 + lr] = sacc[mi][ni][r] + bsv;
      }
    }
  }
  __syncthreads();
  // P1r -> W1r
  stageX(slotO); __syncthreads();
  proj(W1r, oacc);

  // load all V values before any out store (out overwrites V region for node>=128)
  const unsigned short* Vu = slotO + 32768;
  u16x4 vv[4][4];
  #pragma unroll
  for (int mi = 0; mi < 4; ++mi){
    #pragma unroll
    for (int ni = 0; ni < 4; ++ni){
      #pragma unroll
      for (int r = 0; r < 4; ++r)
        vv[mi][ni][r] = Vu[(size_t)(w*64 + mi*16 + q*4 + r)*64 + ni*16 + lr];
    }
  }
  __syncthreads();

  const float* xs = x + (size_t)bt*32768;
  float* op = outp + (size_t)bt*32768;
  #pragma unroll
  for (int ni = 0; ni < 4; ++ni){
    float bsv = bgf[ni*16 + lr] + bgr[ni*16 + lr];
    #pragma unroll
    for (int mi = 0; mi < 4; ++mi){
      #pragma unroll
      for (int r = 0; r < 4; ++r){
        int idx = (w*64 + mi*16 + q*4 + r)*64 + ni*16 + lr;
        op[idx] = oacc[mi][ni][r] + bf2f(vv[mi][ni][r]) + xs[idx] + bsv;
      }
    }
  }
}

extern "C" void kernel_launch(void* const* d_in, const int* in_sizes, int n_in,
                              void* d_out, int out_size, void* d_ws, size_t ws_size,
                              hipStream_t stream){
  const float* x   = (const float*)d_in[0];
  const float* adj = (const float*)d_in[1];
  const float* wf0 = (const float*)d_in[2];
  const float* bf0 = (const float*)d_in[3];
  const float* wg0 = (const float*)d_in[4];
  const float* bg0 = (const float*)d_in[5];
  const float* wf1 = (const float*)d_in[6];
  const float* bf1 = (const float*)d_in[7];
  const float* wg1 = (const float*)d_in[8];
  const float* bg1 = (const float*)d_in[9];
  const float* wf2 = (const float*)d_in[10];
  const float* bf2 = (const float*)d_in[11];
  const float* wg2 = (const float*)d_in[12];
  const float* bg2 = (const float*)d_in[13];
  const float* wf3 = (const float*)d_in[14];
  const float* bf3 = (const float*)d_in[15];
  const float* wg3 = (const float*)d_in[16];
  const float* bg3 = (const float*)d_in[17];
  const float* Wgf = (const float*)d_in[18];
  const float* bgf = (const float*)d_in[19];
  const float* Wgr = (const float*)d_in[20];
  const float* bgr = (const float*)d_in[21];
  const float* Ws  = (const float*)d_in[22];
  const float* bs  = (const float*)d_in[23];

  float* outp  = (float*)d_out;
  float* skipp = outp + (size_t)67108864;          // second output region
  unsigned short* skipU = (unsigned short*)skipp;  // per-bt 128KB slots: [H | P1f]
  unsigned short* outU  = (unsigned short*)outp;   // per-bt 128KB slots: [P1r | V]
  unsigned short* hT = skipU;                      // conv writes H into skip-slot lo halves

  unsigned short* Af  = (unsigned short*)d_ws;     // ws layout (~1.2 MB total)
  unsigned short* Ar  = Af  + 512*512;
  unsigned short* WF  = Ar  + 512*512;
  unsigned short* WG  = WF  + 64*448;
  unsigned short* W0  = WG  + 64*448;
  unsigned short* W1f = W0  + 4096;
  unsigned short* W2f = W1f + 4096;
  unsigned short* W1r = W2f + 4096;
  unsigned short* W2r = W1r + 4096;
  unsigned short* WsT = W2r + 4096;

  k_adj <<<512, 256, 0, stream>>>(adj, Af, Ar);
  k_wcat<<<112, 256, 0, stream>>>(wf0,wf1,wf2,wf3, wg0,wg1,wg2,wg3, WF, WG);
  k_wtil<<<16,  256, 0, stream>>>(Wgf, Wgr, Ws, W0, W1f, W2f, W1r, W2r, WsT);
  k_conv<<<dim3(8,8,8), 256, 0, stream>>>(x, WF, WG, bf0,bf1,bf2,bf3, bg0,bg1,bg2,bg3, hT);
  k_pp  <<<dim3(512,4), 512, 0, stream>>>(Af, Ar, skipU, outU);
  k_p2  <<<dim3(512,4), 512, 0, stream>>>(Af, skipU + 32768, W2f, outU, 0);
  k_p2  <<<dim3(512,4), 512, 0, stream>>>(Ar, outU,          W2r, outU, 1);
  k_out <<<dim3(256,8), 512, 0, stream>>>(x, skipU, outU, W0, W1f, W1r, WsT,
                                          bgf, bgr, bs, outp, skipp);
}